// Round 6
// baseline (272.176 us; speedup 1.0000x reference)
//
#include <hip/hip_runtime.h>

#define N_NODES 75000
#define N_EDGES 1200000
#define DIM 64
#define SCAN_BLK 1024
#define N_SCAN_BLKS ((N_NODES + SCAN_BLK - 1) / SCAN_BLK)   // 74
#define NCOPY 8
#define HIST_BLKS 1172                                      // 1024 edges/block
#define NW_BLKS 586                                         // node_wave blocks
#define FAT_BLKS (HIST_BLKS + NW_BLKS)                      // 1758 = 3*586

// Broadcast lane l (wave-uniform) of v to all lanes via v_readlane (VALU).
__device__ __forceinline__ float lane_bcf(float v, int l) {
    return __int_as_float(__builtin_amdgcn_readlane(__float_as_int(v), l));
}
__device__ __forceinline__ int lane_bci(int v, int l) {
    return __builtin_amdgcn_readlane(v, l);
}

// ---------------------------------------------------------------------------
// FAT KERNEL, ROLE-INTERLEAVED. R3/R4 fused sequentially (hist blocks
// 0..1171 first) and got time == sum: dispatch order meant hist blocks
// filled every CU slot and node_wave only started as hist drained. The
// hist phase is a fabric atomic-rate floor (~24 G atomic/s: 42MB write =
// 1.2M x 32B granule write-through, invariant across R2/R5 configs), with
// CUs ~idle (0.5% VALU). So interleave roles with period 3 (2 hist : 1 nw):
// both co-resident from the start, nw's VALU/BW work fills atomic stalls.
//   r = blockIdx%3: r<2 -> hist block 2*(blockIdx/3)+r; r==2 -> nw blockIdx/3.
// hist keys its cnt8 copy by the REAL XCD id (s_getreg XCC_ID) and packs the
// copy into rank's high bits (copy<<28) for build.
// a/b (f64, same j-order as original -> bit-exact) computed per-block in LDS.
// ---------------------------------------------------------------------------
__global__ __launch_bounds__(256, 4) void fat_kernel(
    const int* __restrict__ dst, int* __restrict__ cnt8, int* __restrict__ rank,
    const float* __restrict__ d_u, const float* __restrict__ p_u,
    const float* __restrict__ w_v, const float* __restrict__ w_q,
    const float* __restrict__ w_k,
    const float* __restrict__ e1, const float* __restrict__ e2,
    double* __restrict__ h_src, double* __restrict__ h_dst,
    float* __restrict__ wv_out) {

    int b = blockIdx.x;
    int g = b / 3;
    int r = b - 3 * g;

    if (r < 2) {
        // ---- histogram path: block id hb in [0, HIST_BLKS) ----
        int hb = 2 * g + r;
        int xcc;
        asm volatile("s_getreg_b32 %0, hwreg(HW_REG_XCC_ID)" : "=s"(xcc));
        xcc &= (NCOPY - 1);
        int* mycnt = cnt8 + (size_t)xcc * N_NODES;
        int tag = xcc << 28;
        int base = hb << 10;                     // 1024 edges per block
        #pragma unroll
        for (int k = 0; k < 4; ++k) {
            int e = base + k * 256 + threadIdx.x;
            if (e < N_EDGES) {
                int rr = atomicAdd(&mycnt[dst[e]], 1);
                rank[e] = rr | tag;
            }
        }
        return;
    }

    // ---- node_wave path: nw block id g in [0, NW_BLKS) ----
    __shared__ double al_sh[DIM];
    __shared__ double bl_sh[DIM];
    int lane = threadIdx.x & 63;

    if (threadIdx.x < DIM) {
        double al = 0.0, bl = 0.0;
        #pragma unroll 8
        for (int j = 0; j < DIM; ++j) {
            al += (double)e1[j] * (double)w_k[j * DIM + threadIdx.x];
            bl += (double)e2[j] * (double)w_q[j * DIM + threadIdx.x];
        }
        al_sh[threadIdx.x] = al;
        bl_sh[threadIdx.x] = bl;
    }

    float w[DIM];
    const float4* wr = (const float4*)(w_v + (size_t)lane * DIM);
    #pragma unroll
    for (int k = 0; k < DIM / 4; ++k) {
        float4 v = wr[k];
        w[4 * k + 0] = v.x; w[4 * k + 1] = v.y;
        w[4 * k + 2] = v.z; w[4 * k + 3] = v.w;
    }
    __syncthreads();
    double al = al_sh[lane];
    double bl = bl_sh[lane];

    int wave = (g * 256 + threadIdx.x) >> 6;
    int nwaves = NW_BLKS * 4;

    for (int i = wave; i < N_NODES; i += nwaves) {
        float pl = p_u[(size_t)i * DIM + lane];
        float dl = d_u[(size_t)i * DIM + lane];

        double hs = (double)pl * al;
        #pragma unroll
        for (int off = 32; off > 0; off >>= 1) hs += __shfl_xor(hs, off, 64);
        double hd = (double)dl * bl;
        #pragma unroll
        for (int off = 32; off > 0; off >>= 1) hd += __shfl_xor(hd, off, 64);
        if (lane == 0) { h_src[i] = hs; h_dst[i] = hd; }

        float a0 = 0.f, a1 = 0.f, a2 = 0.f, a3 = 0.f;
        #pragma unroll
        for (int d = 0; d < DIM; d += 4) {
            a0 += w[d + 0] * lane_bcf(pl, d + 0);
            a1 += w[d + 1] * lane_bcf(pl, d + 1);
            a2 += w[d + 2] * lane_bcf(pl, d + 2);
            a3 += w[d + 3] * lane_bcf(pl, d + 3);
        }
        wv_out[(size_t)i * DIM + lane] = (a0 + a1) + (a2 + a3);
    }
}

// ---------------------------------------------------------------------------
// Fused CSR scan (replaces scan1+scan23): fold the 8 cnt8 copies into
// per-copy exclusive prefixes (in place), degree -> cnt, block-local
// Hillis-Steele, then cross-block prefix via publish/spin lookback:
// each block publishes its inclusive total with a flag bit (device-scope
// atomicExch); wave 0 spins reading earlier blocks' totals (<= 74 words,
// all blocks co-resident -> no deadlock) and butterfly-sums them.
// ---------------------------------------------------------------------------
__global__ __launch_bounds__(SCAN_BLK) void scan_kernel(
    int* __restrict__ cnt8, int* __restrict__ cnt,
    int* __restrict__ row, unsigned int* __restrict__ pub) {
    __shared__ int sh[SCAN_BLK];
    __shared__ int bpref;
    int tid = threadIdx.x;
    int i = blockIdx.x * SCAN_BLK + tid;
    int v = 0;
    if (i < N_NODES) {
        int run = 0;
        #pragma unroll
        for (int c = 0; c < NCOPY; ++c) {
            int x = cnt8[(size_t)c * N_NODES + i];
            cnt8[(size_t)c * N_NODES + i] = run;   // P[c][i] = prefix
            run += x;
        }
        v = run;
        cnt[i] = run;                              // degree
    }
    sh[tid] = v;
    __syncthreads();
    for (int off = 1; off < SCAN_BLK; off <<= 1) {
        int t = (tid >= off) ? sh[tid - off] : 0;
        __syncthreads();
        sh[tid] += t;
        __syncthreads();
    }
    int incl = sh[tid];
    if (tid == SCAN_BLK - 1)                       // block total = incl here
        atomicExch(&pub[blockIdx.x], (unsigned)incl | 0x80000000u);
    if (tid < 64) {
        int s = 0;
        for (int l = tid; l < (int)blockIdx.x; l += 64) {
            unsigned x;
            do { x = atomicAdd(&pub[l], 0u); } while (!(x & 0x80000000u));
            s += (int)(x & 0x7FFFFFFFu);
        }
        #pragma unroll
        for (int off = 32; off > 0; off >>= 1) s += __shfl_xor(s, off, 64);
        if (tid == 0) bpref = s;
    }
    __syncthreads();
    if (i < N_NODES) row[i] = bpref + incl - v;    // exclusive global prefix
}

// CSR step 3: atomic-free scatter of src ids.
//   pos = row[d] + P[copy][d] + r,  rank[e] packs (copy<<28 | r).
// csr_src store is NONTEMPORAL: 4B scattered stores otherwise trigger
// read-for-ownership write-allocate (R1 fused counters: 79MB writes for
// 4.8MB of data). nt = no-allocate; gather re-reads 4.8MB from HBM (~1us)
// against a predicted ~60MB write saving. Revert if WRITE_SIZE unchanged.
__global__ __launch_bounds__(256) void build_kernel(
    const int* __restrict__ src, const int* __restrict__ dst,
    const int* __restrict__ row, const int* __restrict__ cnt8,
    const int* __restrict__ rank, int* __restrict__ csr_src) {
    int e = blockIdx.x * 256 + threadIdx.x;
    if (e >= N_EDGES) return;
    int d = dst[e];
    int rp = rank[e];
    int copy = (rp >> 28) & (NCOPY - 1);
    int r = rp & 0x0FFFFFFF;
    int pos = row[d] + cnt8[(size_t)copy * N_NODES + d] + r;
    __builtin_nontemporal_store(src[e], &csr_src[pos]);
}

// ---------------------------------------------------------------------------
// Gather: one wave per dst node, grouped float4 row gather — 4 groups of 16
// lanes each load a DIFFERENT edge's 256B wv row as float4 (one dwordx4
// covers 4 rows). f64 butterfly denom kept; rounds skipped for small deg.
// ---------------------------------------------------------------------------
__global__ __launch_bounds__(256) void node_gather(
    const int* __restrict__ row, const int* __restrict__ cnt,
    const int* __restrict__ csr_src,
    const double* __restrict__ h_src, const double* __restrict__ h_dst,
    const float* __restrict__ wv, float* __restrict__ out) {
    int gtid = blockIdx.x * 256 + threadIdx.x;
    int node = gtid >> 6;
    int lane = threadIdx.x & 63;
    if (node >= N_NODES) return;

    int start = row[node];
    int deg = cnt[node];
    double hd = h_dst[node];

    if (deg <= 64) {
        int s0 = 0;
        double c0 = 0.0;
        if (lane < deg) {
            s0 = csr_src[start + lane];
            c0 = h_src[s0] + hd;
        }
        double r = c0;
        if (deg > 32) r += __shfl_xor(r, 32, 64);
        if (deg > 16) r += __shfl_xor(r, 16, 64);
        r += __shfl_xor(r, 8, 64);
        r += __shfl_xor(r, 4, 64);
        r += __shfl_xor(r, 2, 64);
        r += __shfl_xor(r, 1, 64);
        double inv = 1.0 / r;
        float cf0 = (lane < deg) ? (float)(c0 * inv) : 0.f;
        // padded lanes (>= deg): s0 = 0 (valid row), cf0 = 0 -> no-op terms.

        int g = lane >> 4;          // group 0..3 = which edge of the quartet
        int sub = lane & 15;        // float4 slot within the 256B row
        float ax = 0.f, ay = 0.f, az = 0.f, aw = 0.f;
        int rounds = (deg + 3) >> 2;
        int j = 0;
        for (; j + 2 <= rounds; j += 2) {
            int l0 = 4 * j + g;
            int l1 = l0 + 4;
            int   sA = __shfl(s0, l0, 64);
            float cA = __shfl(cf0, l0, 64);
            int   sB = __shfl(s0, l1, 64);
            float cB = __shfl(cf0, l1, 64);
            float4 vA = ((const float4*)(wv + (size_t)sA * DIM))[sub];
            float4 vB = ((const float4*)(wv + (size_t)sB * DIM))[sub];
            ax += vA.x * cA; ay += vA.y * cA; az += vA.z * cA; aw += vA.w * cA;
            ax += vB.x * cB; ay += vB.y * cB; az += vB.z * cB; aw += vB.w * cB;
        }
        if (j < rounds) {
            int l0 = 4 * j + g;
            int   sA = __shfl(s0, l0, 64);
            float cA = __shfl(cf0, l0, 64);
            float4 vA = ((const float4*)(wv + (size_t)sA * DIM))[sub];
            ax += vA.x * cA; ay += vA.y * cA; az += vA.z * cA; aw += vA.w * cA;
        }
        ax += __shfl_xor(ax, 16, 64); ay += __shfl_xor(ay, 16, 64);
        az += __shfl_xor(az, 16, 64); aw += __shfl_xor(aw, 16, 64);
        ax += __shfl_xor(ax, 32, 64); ay += __shfl_xor(ay, 32, 64);
        az += __shfl_xor(az, 32, 64); aw += __shfl_xor(aw, 32, 64);
        if (g == 0) {
            float4 o; o.x = ax; o.y = ay; o.z = az; o.w = aw;
            ((float4*)(out + (size_t)node * DIM))[sub] = o;
        }
    } else {
        double denom = 0.0;
        for (int base = 0; base < deg; base += 64) {
            int m = deg - base; if (m > 64) m = 64;
            double c = 0.0;
            if (lane < m) {
                int s = csr_src[start + base + lane];
                c = h_src[s] + hd;
            }
            #pragma unroll
            for (int off = 32; off > 0; off >>= 1) c += __shfl_xor(c, off, 64);
            denom += c;
        }
        double inv = 1.0 / denom;
        float acc = 0.f;
        for (int base = 0; base < deg; base += 64) {
            int m = deg - base; if (m > 64) m = 64;
            int s1 = 0; float cf1 = 0.f;
            if (lane < m) {
                s1 = csr_src[start + base + lane];
                cf1 = (float)((h_src[s1] + hd) * inv);
            }
            for (int j = 0; j < m; ++j) {
                int s = lane_bci(s1, j);
                float cf = lane_bcf(cf1, j);
                acc += wv[(size_t)s * DIM + lane] * cf;
            }
        }
        out[(size_t)node * DIM + lane] = acc;
    }
}

// ---------------------------------------------------------------------------
// Launch — 5 dispatches (was 8): memset, fat, scan, build, gather.
// ---------------------------------------------------------------------------
extern "C" void kernel_launch(void* const* d_in, const int* in_sizes, int n_in,
                              void* d_out, int out_size, void* d_ws, size_t ws_size,
                              hipStream_t stream) {
    const float* d_u = (const float*)d_in[0];
    const float* p_u = (const float*)d_in[1];
    const float* w_q = (const float*)d_in[2];
    const float* w_k = (const float*)d_in[3];
    const float* w_v = (const float*)d_in[4];
    const float* e1  = (const float*)d_in[5];
    const float* e2  = (const float*)d_in[6];
    const int*   src = (const int*)d_in[7];
    const int*   dst = (const int*)d_in[8];
    float* out = (float*)d_out;

    // Workspace: doubles first (8B aligned), then floats, then ints.
    double* h_src  = (double*)d_ws;
    double* h_dst  = h_src + N_NODES;
    float*  wv     = (float*)(h_dst + N_NODES);       // N_NODES*DIM floats
    int*    cnt    = (int*)(wv + (size_t)N_NODES * DIM);
    int*    row    = cnt + N_NODES;
    int*    cnt8   = row + N_NODES;                   // NCOPY*N_NODES ints
    unsigned int* pub = (unsigned int*)(cnt8 + (size_t)NCOPY * N_NODES); // 128
    int*    rank   = (int*)pub + 128;                 // N_EDGES ints
    int*    csr_src= rank + N_EDGES;                  // N_EDGES ints

    // zero cnt8 + pub in one memset (contiguous)
    hipMemsetAsync(cnt8, 0, sizeof(int) * ((size_t)NCOPY * N_NODES + 128),
                   stream);

    fat_kernel<<<FAT_BLKS, 256, 0, stream>>>(
        dst, cnt8, rank, d_u, p_u, w_v, w_q, w_k, e1, e2, h_src, h_dst, wv);

    scan_kernel<<<N_SCAN_BLKS, SCAN_BLK, 0, stream>>>(cnt8, cnt, row, pub);

    build_kernel<<<(N_EDGES + 255) / 256, 256, 0, stream>>>(
        src, dst, row, cnt8, rank, csr_src);

    node_gather<<<(N_NODES * 64 + 255) / 256, 256, 0, stream>>>(
        row, cnt, csr_src, h_src, h_dst, wv, out);
}

// Round 7
// 267.138 us; speedup vs baseline: 1.0189x; 1.0189x over previous
//
#include <hip/hip_runtime.h>

#define N_NODES 75000
#define N_EDGES 1200000
#define DIM 64
#define SCAN_BLK 1024
#define N_SCAN_BLKS ((N_NODES + SCAN_BLK - 1) / SCAN_BLK)   // 74
#define NCOPY 8
#define HIST_BLKS ((N_EDGES + 1023) / 1024)                 // 1172, 1024 edges/block

// Broadcast lane l (wave-uniform) of v to all lanes via v_readlane (VALU).
__device__ __forceinline__ float lane_bcf(float v, int l) {
    return __int_as_float(__builtin_amdgcn_readlane(__float_as_int(v), l));
}
__device__ __forceinline__ int lane_bci(int v, int l) {
    return __builtin_amdgcn_readlane(v, l);
}

// ---------------------------------------------------------------------------
// Kernel A (f64): a[d] = sum_j e1[j]*w_k[j][d];  b[d] = sum_j e2[j]*w_q[j][d]
// ---------------------------------------------------------------------------
__global__ void vec_precompute(const float* __restrict__ w_q,
                               const float* __restrict__ w_k,
                               const float* __restrict__ e1,
                               const float* __restrict__ e2,
                               double* __restrict__ a,
                               double* __restrict__ b) {
    int t = threadIdx.x;
    if (t < DIM) {
        double s = 0.0;
        #pragma unroll
        for (int j = 0; j < DIM; ++j) s += (double)e1[j] * (double)w_k[j * DIM + t];
        a[t] = s;
    } else if (t < 2 * DIM) {
        int d = t - DIM;
        double s = 0.0;
        #pragma unroll
        for (int j = 0; j < DIM; ++j) s += (double)e2[j] * (double)w_q[j * DIM + d];
        b[d] = s;
    }
}

// ---------------------------------------------------------------------------
// CSR step 1: histogram with NEAR ATOMICS.
// R2-R6 evidence: plain atomicAdd (agent scope) on the 8-XCD-non-coherent
// MI355X cannot execute in a local L2 -> it is a FAR atomic at the memory
// fabric: 24 G/s floor, 32B write-through per op (42MB WRITE_SIZE), immune
// to privatization and to co-scheduled work (shared fabric path — why both
// fusion attempts gave time==sum). Fix: WORKGROUP-scope atomic -> executes
// as a near atomic in the local XCD L2. Correctness: every atomic to copy c
// is issued from XCD c (hardware XCC_ID keying), so all ops on a copy meet
// at one L2 and serialize there; the dispatch-boundary release makes the
// results visible to the next kernel (same mechanism as our plain stores).
// copy id packed into rank's high bits (rank < 2^28) for build.
// ---------------------------------------------------------------------------
__global__ __launch_bounds__(256) void hist_kernel(
    const int* __restrict__ dst, int* __restrict__ cnt8,
    int* __restrict__ rank) {
    int xcc;
    asm volatile("s_getreg_b32 %0, hwreg(HW_REG_XCC_ID)" : "=s"(xcc));
    xcc &= (NCOPY - 1);
    int* mycnt = cnt8 + (size_t)xcc * N_NODES;
    int tag = xcc << 28;
    int base = blockIdx.x << 10;                 // 1024 edges per block
    #pragma unroll
    for (int k = 0; k < 4; ++k) {
        int e = base + k * 256 + threadIdx.x;
        if (e < N_EDGES) {
            int r = __hip_atomic_fetch_add(&mycnt[dst[e]], 1,
                                           __ATOMIC_RELAXED,
                                           __HIP_MEMORY_SCOPE_WORKGROUP);
            rank[e] = r | tag;
        }
    }
}

// ---------------------------------------------------------------------------
// Fused node precompute: ONE WAVE PER NODE (grid-strided). R2 version.
// ---------------------------------------------------------------------------
__global__ __launch_bounds__(256, 4) void node_wave(
    const float* __restrict__ d_u, const float* __restrict__ p_u,
    const float* __restrict__ w_v,
    const double* __restrict__ a_vec, const double* __restrict__ b_vec,
    double* __restrict__ h_src, double* __restrict__ h_dst,
    float* __restrict__ wv_out) {
    int lane = threadIdx.x & 63;
    int wave = (blockIdx.x * 256 + threadIdx.x) >> 6;
    int nwaves = gridDim.x * 4;

    float w[DIM];
    const float4* wr = (const float4*)(w_v + (size_t)lane * DIM);
    #pragma unroll
    for (int k = 0; k < DIM / 4; ++k) {
        float4 v = wr[k];
        w[4 * k + 0] = v.x; w[4 * k + 1] = v.y;
        w[4 * k + 2] = v.z; w[4 * k + 3] = v.w;
    }
    double al = a_vec[lane];
    double bl = b_vec[lane];

    for (int i = wave; i < N_NODES; i += nwaves) {
        float pl = p_u[(size_t)i * DIM + lane];
        float dl = d_u[(size_t)i * DIM + lane];

        double hs = (double)pl * al;
        #pragma unroll
        for (int off = 32; off > 0; off >>= 1) hs += __shfl_xor(hs, off, 64);
        double hd = (double)dl * bl;
        #pragma unroll
        for (int off = 32; off > 0; off >>= 1) hd += __shfl_xor(hd, off, 64);
        if (lane == 0) { h_src[i] = hs; h_dst[i] = hd; }

        float a0 = 0.f, a1 = 0.f, a2 = 0.f, a3 = 0.f;
        #pragma unroll
        for (int d = 0; d < DIM; d += 4) {
            a0 += w[d + 0] * lane_bcf(pl, d + 0);
            a1 += w[d + 1] * lane_bcf(pl, d + 1);
            a2 += w[d + 2] * lane_bcf(pl, d + 2);
            a3 += w[d + 3] * lane_bcf(pl, d + 3);
        }
        wv_out[(size_t)i * DIM + lane] = (a0 + a1) + (a2 + a3);
    }
}

// ---------------------------------------------------------------------------
// Fused CSR scan: fold the 8 cnt8 copies into per-copy exclusive prefixes
// (in place), degree -> cnt, block-local Hillis-Steele, then cross-block
// prefix via publish/spin lookback (device-scope; 74 words, all blocks
// co-resident -> no deadlock).
// ---------------------------------------------------------------------------
__global__ __launch_bounds__(SCAN_BLK) void scan_kernel(
    int* __restrict__ cnt8, int* __restrict__ cnt,
    int* __restrict__ row, unsigned int* __restrict__ pub) {
    __shared__ int sh[SCAN_BLK];
    __shared__ int bpref;
    int tid = threadIdx.x;
    int i = blockIdx.x * SCAN_BLK + tid;
    int v = 0;
    if (i < N_NODES) {
        int run = 0;
        #pragma unroll
        for (int c = 0; c < NCOPY; ++c) {
            int x = cnt8[(size_t)c * N_NODES + i];
            cnt8[(size_t)c * N_NODES + i] = run;   // P[c][i] = prefix
            run += x;
        }
        v = run;
        cnt[i] = run;                              // degree
    }
    sh[tid] = v;
    __syncthreads();
    for (int off = 1; off < SCAN_BLK; off <<= 1) {
        int t = (tid >= off) ? sh[tid - off] : 0;
        __syncthreads();
        sh[tid] += t;
        __syncthreads();
    }
    int incl = sh[tid];
    if (tid == SCAN_BLK - 1)                       // block total = incl here
        atomicExch(&pub[blockIdx.x], (unsigned)incl | 0x80000000u);
    if (tid < 64) {
        int s = 0;
        for (int l = tid; l < (int)blockIdx.x; l += 64) {
            unsigned x;
            do { x = atomicAdd(&pub[l], 0u); } while (!(x & 0x80000000u));
            s += (int)(x & 0x7FFFFFFFu);
        }
        #pragma unroll
        for (int off = 32; off > 0; off >>= 1) s += __shfl_xor(s, off, 64);
        if (tid == 0) bpref = s;
    }
    __syncthreads();
    if (i < N_NODES) row[i] = bpref + incl - v;    // exclusive global prefix
}

// CSR step 3: atomic-free scatter of src ids.
//   pos = row[d] + P[copy][d] + r,  rank[e] packs (copy<<28 | r).
// nt store: scattered 4B stores otherwise trigger read-for-ownership
// write-allocate (R1: 79MB writes for 4.8MB of data).
__global__ __launch_bounds__(256) void build_kernel(
    const int* __restrict__ src, const int* __restrict__ dst,
    const int* __restrict__ row, const int* __restrict__ cnt8,
    const int* __restrict__ rank, int* __restrict__ csr_src) {
    int e = blockIdx.x * 256 + threadIdx.x;
    if (e >= N_EDGES) return;
    int d = dst[e];
    int rp = rank[e];
    int copy = (rp >> 28) & (NCOPY - 1);
    int r = rp & 0x0FFFFFFF;
    int pos = row[d] + cnt8[(size_t)copy * N_NODES + d] + r;
    __builtin_nontemporal_store(src[e], &csr_src[pos]);
}

// ---------------------------------------------------------------------------
// Gather: one wave per dst node, grouped float4 row gather — 4 groups of 16
// lanes each load a DIFFERENT edge's 256B wv row as float4 (one dwordx4
// covers 4 rows). f64 butterfly denom kept; rounds skipped for small deg.
// ---------------------------------------------------------------------------
__global__ __launch_bounds__(256) void node_gather(
    const int* __restrict__ row, const int* __restrict__ cnt,
    const int* __restrict__ csr_src,
    const double* __restrict__ h_src, const double* __restrict__ h_dst,
    const float* __restrict__ wv, float* __restrict__ out) {
    int gtid = blockIdx.x * 256 + threadIdx.x;
    int node = gtid >> 6;
    int lane = threadIdx.x & 63;
    if (node >= N_NODES) return;

    int start = row[node];
    int deg = cnt[node];
    double hd = h_dst[node];

    if (deg <= 64) {
        int s0 = 0;
        double c0 = 0.0;
        if (lane < deg) {
            s0 = csr_src[start + lane];
            c0 = h_src[s0] + hd;
        }
        double r = c0;
        if (deg > 32) r += __shfl_xor(r, 32, 64);
        if (deg > 16) r += __shfl_xor(r, 16, 64);
        r += __shfl_xor(r, 8, 64);
        r += __shfl_xor(r, 4, 64);
        r += __shfl_xor(r, 2, 64);
        r += __shfl_xor(r, 1, 64);
        double inv = 1.0 / r;
        float cf0 = (lane < deg) ? (float)(c0 * inv) : 0.f;
        // padded lanes (>= deg): s0 = 0 (valid row), cf0 = 0 -> no-op terms.

        int g = lane >> 4;          // group 0..3 = which edge of the quartet
        int sub = lane & 15;        // float4 slot within the 256B row
        float ax = 0.f, ay = 0.f, az = 0.f, aw = 0.f;
        int rounds = (deg + 3) >> 2;
        int j = 0;
        for (; j + 2 <= rounds; j += 2) {
            int l0 = 4 * j + g;
            int l1 = l0 + 4;
            int   sA = __shfl(s0, l0, 64);
            float cA = __shfl(cf0, l0, 64);
            int   sB = __shfl(s0, l1, 64);
            float cB = __shfl(cf0, l1, 64);
            float4 vA = ((const float4*)(wv + (size_t)sA * DIM))[sub];
            float4 vB = ((const float4*)(wv + (size_t)sB * DIM))[sub];
            ax += vA.x * cA; ay += vA.y * cA; az += vA.z * cA; aw += vA.w * cA;
            ax += vB.x * cB; ay += vB.y * cB; az += vB.z * cB; aw += vB.w * cB;
        }
        if (j < rounds) {
            int l0 = 4 * j + g;
            int   sA = __shfl(s0, l0, 64);
            float cA = __shfl(cf0, l0, 64);
            float4 vA = ((const float4*)(wv + (size_t)sA * DIM))[sub];
            ax += vA.x * cA; ay += vA.y * cA; az += vA.z * cA; aw += vA.w * cA;
        }
        ax += __shfl_xor(ax, 16, 64); ay += __shfl_xor(ay, 16, 64);
        az += __shfl_xor(az, 16, 64); aw += __shfl_xor(aw, 16, 64);
        ax += __shfl_xor(ax, 32, 64); ay += __shfl_xor(ay, 32, 64);
        az += __shfl_xor(az, 32, 64); aw += __shfl_xor(aw, 32, 64);
        if (g == 0) {
            float4 o; o.x = ax; o.y = ay; o.z = az; o.w = aw;
            ((float4*)(out + (size_t)node * DIM))[sub] = o;
        }
    } else {
        double denom = 0.0;
        for (int base = 0; base < deg; base += 64) {
            int m = deg - base; if (m > 64) m = 64;
            double c = 0.0;
            if (lane < m) {
                int s = csr_src[start + base + lane];
                c = h_src[s] + hd;
            }
            #pragma unroll
            for (int off = 32; off > 0; off >>= 1) c += __shfl_xor(c, off, 64);
            denom += c;
        }
        double inv = 1.0 / denom;
        float acc = 0.f;
        for (int base = 0; base < deg; base += 64) {
            int m = deg - base; if (m > 64) m = 64;
            int s1 = 0; float cf1 = 0.f;
            if (lane < m) {
                s1 = csr_src[start + base + lane];
                cf1 = (float)((h_src[s1] + hd) * inv);
            }
            for (int j = 0; j < m; ++j) {
                int s = lane_bci(s1, j);
                float cf = lane_bcf(cf1, j);
                acc += wv[(size_t)s * DIM + lane] * cf;
            }
        }
        out[(size_t)node * DIM + lane] = acc;
    }
}

// ---------------------------------------------------------------------------
// Launch — memset, vec, hist, node_wave, scan, build, gather.
// ---------------------------------------------------------------------------
extern "C" void kernel_launch(void* const* d_in, const int* in_sizes, int n_in,
                              void* d_out, int out_size, void* d_ws, size_t ws_size,
                              hipStream_t stream) {
    const float* d_u = (const float*)d_in[0];
    const float* p_u = (const float*)d_in[1];
    const float* w_q = (const float*)d_in[2];
    const float* w_k = (const float*)d_in[3];
    const float* w_v = (const float*)d_in[4];
    const float* e1  = (const float*)d_in[5];
    const float* e2  = (const float*)d_in[6];
    const int*   src = (const int*)d_in[7];
    const int*   dst = (const int*)d_in[8];
    float* out = (float*)d_out;

    // Workspace: doubles first (8B aligned), then floats, then ints.
    double* a      = (double*)d_ws;
    double* b      = a + DIM;
    double* h_src  = b + DIM;
    double* h_dst  = h_src + N_NODES;
    float*  wv     = (float*)(h_dst + N_NODES);       // N_NODES*DIM floats
    int*    cnt    = (int*)(wv + (size_t)N_NODES * DIM);
    int*    row    = cnt + N_NODES;
    int*    cnt8   = row + N_NODES;                   // NCOPY*N_NODES ints
    unsigned int* pub = (unsigned int*)(cnt8 + (size_t)NCOPY * N_NODES); // 128
    int*    rank   = (int*)pub + 128;                 // N_EDGES ints
    int*    csr_src= rank + N_EDGES;                  // N_EDGES ints

    // zero cnt8 + pub in one memset (contiguous)
    hipMemsetAsync(cnt8, 0, sizeof(int) * ((size_t)NCOPY * N_NODES + 128),
                   stream);

    vec_precompute<<<1, 128, 0, stream>>>(w_q, w_k, e1, e2, a, b);

    hist_kernel<<<HIST_BLKS, 256, 0, stream>>>(dst, cnt8, rank);

    node_wave<<<1024, 256, 0, stream>>>(
        d_u, p_u, w_v, a, b, h_src, h_dst, wv);

    scan_kernel<<<N_SCAN_BLKS, SCAN_BLK, 0, stream>>>(cnt8, cnt, row, pub);

    build_kernel<<<(N_EDGES + 255) / 256, 256, 0, stream>>>(
        src, dst, row, cnt8, rank, csr_src);

    node_gather<<<(N_NODES * 64 + 255) / 256, 256, 0, stream>>>(
        row, cnt, csr_src, h_src, h_dst, wv, out);
}

// Round 8
// 261.755 us; speedup vs baseline: 1.0398x; 1.0206x over previous
//
#include <hip/hip_runtime.h>

#define N_NODES 75000
#define N_EDGES 1200000
#define DIM 64
#define SCAN_BLK 1024
#define N_SCAN_BLKS ((N_NODES + SCAN_BLK - 1) / SCAN_BLK)   // 74
#define NCOPY 8
#define HIST_BLKS ((N_EDGES + 1023) / 1024)                 // 1172, 1024 edges/block

typedef _Float16 half8 __attribute__((ext_vector_type(8)));  // 16B = 8 halfs

// Broadcast lane l (wave-uniform) of v to all lanes via v_readlane (VALU).
__device__ __forceinline__ float lane_bcf(float v, int l) {
    return __int_as_float(__builtin_amdgcn_readlane(__float_as_int(v), l));
}
__device__ __forceinline__ int lane_bci(int v, int l) {
    return __builtin_amdgcn_readlane(v, l);
}

// ---------------------------------------------------------------------------
// CSR step 1: histogram. R2-R7 established the ~25 G atomic/s memory-side
// floor (invariant under copy-privatization, XCC keying, scope, edges/thread,
// co-scheduled work). Keep the simple form; copy id (XCC) packed into rank's
// high bits for build. Beating this needs an atomic-free sort — deferred.
// ---------------------------------------------------------------------------
__global__ __launch_bounds__(256) void hist_kernel(
    const int* __restrict__ dst, int* __restrict__ cnt8,
    int* __restrict__ rank) {
    int xcc;
    asm volatile("s_getreg_b32 %0, hwreg(HW_REG_XCC_ID)" : "=s"(xcc));
    xcc &= (NCOPY - 1);
    int* mycnt = cnt8 + (size_t)xcc * N_NODES;
    int tag = xcc << 28;
    int base = blockIdx.x << 10;                 // 1024 edges per block
    #pragma unroll
    for (int k = 0; k < 4; ++k) {
        int e = base + k * 256 + threadIdx.x;
        if (e < N_EDGES) {
            int r = atomicAdd(&mycnt[dst[e]], 1);
            rank[e] = r | tag;
        }
    }
}

// ---------------------------------------------------------------------------
// Node precompute, ONE WAVE PER NODE (grid-strided), with vec_precompute
// folded in per block (LDS, f64, same j-order -> bit-exact; R3-verified
// pattern). NEW: wv output stored as f16 (halves gather-side row size;
// values O(1), f16 rel err ~5e-4, fp32 accumulation downstream).
// ---------------------------------------------------------------------------
__global__ __launch_bounds__(256, 4) void node_wave(
    const float* __restrict__ d_u, const float* __restrict__ p_u,
    const float* __restrict__ w_v, const float* __restrict__ w_q,
    const float* __restrict__ w_k,
    const float* __restrict__ e1, const float* __restrict__ e2,
    double* __restrict__ h_src, double* __restrict__ h_dst,
    _Float16* __restrict__ wvh) {
    __shared__ double al_sh[DIM];
    __shared__ double bl_sh[DIM];
    int lane = threadIdx.x & 63;

    if (threadIdx.x < DIM) {
        double al = 0.0, bl = 0.0;
        #pragma unroll 8
        for (int j = 0; j < DIM; ++j) {
            al += (double)e1[j] * (double)w_k[j * DIM + threadIdx.x];
            bl += (double)e2[j] * (double)w_q[j * DIM + threadIdx.x];
        }
        al_sh[threadIdx.x] = al;
        bl_sh[threadIdx.x] = bl;
    }

    float w[DIM];
    const float4* wr = (const float4*)(w_v + (size_t)lane * DIM);
    #pragma unroll
    for (int k = 0; k < DIM / 4; ++k) {
        float4 v = wr[k];
        w[4 * k + 0] = v.x; w[4 * k + 1] = v.y;
        w[4 * k + 2] = v.z; w[4 * k + 3] = v.w;
    }
    __syncthreads();
    double al = al_sh[lane];
    double bl = bl_sh[lane];

    int wave = (blockIdx.x * 256 + threadIdx.x) >> 6;
    int nwaves = gridDim.x * 4;

    for (int i = wave; i < N_NODES; i += nwaves) {
        float pl = p_u[(size_t)i * DIM + lane];
        float dl = d_u[(size_t)i * DIM + lane];

        double hs = (double)pl * al;
        #pragma unroll
        for (int off = 32; off > 0; off >>= 1) hs += __shfl_xor(hs, off, 64);
        double hd = (double)dl * bl;
        #pragma unroll
        for (int off = 32; off > 0; off >>= 1) hd += __shfl_xor(hd, off, 64);
        if (lane == 0) { h_src[i] = hs; h_dst[i] = hd; }

        float a0 = 0.f, a1 = 0.f, a2 = 0.f, a3 = 0.f;
        #pragma unroll
        for (int d = 0; d < DIM; d += 4) {
            a0 += w[d + 0] * lane_bcf(pl, d + 0);
            a1 += w[d + 1] * lane_bcf(pl, d + 1);
            a2 += w[d + 2] * lane_bcf(pl, d + 2);
            a3 += w[d + 3] * lane_bcf(pl, d + 3);
        }
        wvh[(size_t)i * DIM + lane] = (_Float16)((a0 + a1) + (a2 + a3));
    }
}

// ---------------------------------------------------------------------------
// Fused CSR scan: fold the 8 cnt8 copies into per-copy exclusive prefixes
// (in place), degree -> cnt, block-local Hillis-Steele, then cross-block
// prefix via publish/spin lookback (74 words, all blocks co-resident).
// ---------------------------------------------------------------------------
__global__ __launch_bounds__(SCAN_BLK) void scan_kernel(
    int* __restrict__ cnt8, int* __restrict__ cnt,
    int* __restrict__ row, unsigned int* __restrict__ pub) {
    __shared__ int sh[SCAN_BLK];
    __shared__ int bpref;
    int tid = threadIdx.x;
    int i = blockIdx.x * SCAN_BLK + tid;
    int v = 0;
    if (i < N_NODES) {
        int run = 0;
        #pragma unroll
        for (int c = 0; c < NCOPY; ++c) {
            int x = cnt8[(size_t)c * N_NODES + i];
            cnt8[(size_t)c * N_NODES + i] = run;   // P[c][i] = prefix
            run += x;
        }
        v = run;
        cnt[i] = run;                              // degree
    }
    sh[tid] = v;
    __syncthreads();
    for (int off = 1; off < SCAN_BLK; off <<= 1) {
        int t = (tid >= off) ? sh[tid - off] : 0;
        __syncthreads();
        sh[tid] += t;
        __syncthreads();
    }
    int incl = sh[tid];
    if (tid == SCAN_BLK - 1)                       // block total = incl here
        atomicExch(&pub[blockIdx.x], (unsigned)incl | 0x80000000u);
    if (tid < 64) {
        int s = 0;
        for (int l = tid; l < (int)blockIdx.x; l += 64) {
            unsigned x;
            do { x = atomicAdd(&pub[l], 0u); } while (!(x & 0x80000000u));
            s += (int)(x & 0x7FFFFFFFu);
        }
        #pragma unroll
        for (int off = 32; off > 0; off >>= 1) s += __shfl_xor(s, off, 64);
        if (tid == 0) bpref = s;
    }
    __syncthreads();
    if (i < N_NODES) row[i] = bpref + incl - v;    // exclusive global prefix
}

// CSR step 3: atomic-free scatter of src ids.
//   pos = row[d] + P[copy][d] + r,  rank[e] packs (copy<<28 | r).
// nt store dodges read-for-ownership write-allocate on scattered 4B stores.
__global__ __launch_bounds__(256) void build_kernel(
    const int* __restrict__ src, const int* __restrict__ dst,
    const int* __restrict__ row, const int* __restrict__ cnt8,
    const int* __restrict__ rank, int* __restrict__ csr_src) {
    int e = blockIdx.x * 256 + threadIdx.x;
    if (e >= N_EDGES) return;
    int d = dst[e];
    int rp = rank[e];
    int copy = (rp >> 28) & (NCOPY - 1);
    int r = rp & 0x0FFFFFFF;
    int pos = row[d] + cnt8[(size_t)copy * N_NODES + d] + r;
    __builtin_nontemporal_store(src[e], &csr_src[pos]);
}

// ---------------------------------------------------------------------------
// Gather: one wave per dst node. f16 wv rows (128B): 8 groups of 8 lanes,
// each group loads a DIFFERENT edge's row as one dwordx4 slice -> one wave
// load instruction covers 8 edges (was 4 at f32), and inner rounds per node
// halve (deg/8). fp32 accumulate; f64 butterfly denom unchanged.
// ---------------------------------------------------------------------------
__global__ __launch_bounds__(256) void node_gather(
    const int* __restrict__ row, const int* __restrict__ cnt,
    const int* __restrict__ csr_src,
    const double* __restrict__ h_src, const double* __restrict__ h_dst,
    const _Float16* __restrict__ wvh, float* __restrict__ out) {
    int gtid = blockIdx.x * 256 + threadIdx.x;
    int node = gtid >> 6;
    int lane = threadIdx.x & 63;
    if (node >= N_NODES) return;

    int start = row[node];
    int deg = cnt[node];
    double hd = h_dst[node];

    if (deg <= 64) {
        int s0 = 0;
        double c0 = 0.0;
        if (lane < deg) {
            s0 = csr_src[start + lane];
            c0 = h_src[s0] + hd;
        }
        // deg is wave-uniform: skip butterfly rounds over all-zero groups.
        double r = c0;
        if (deg > 32) r += __shfl_xor(r, 32, 64);
        if (deg > 16) r += __shfl_xor(r, 16, 64);
        r += __shfl_xor(r, 8, 64);
        r += __shfl_xor(r, 4, 64);
        r += __shfl_xor(r, 2, 64);
        r += __shfl_xor(r, 1, 64);
        double inv = 1.0 / r;
        float cf0 = (lane < deg) ? (float)(c0 * inv) : 0.f;
        // padded lanes (>= deg): s0 = 0 (valid row), cf0 = 0 -> no-op terms.

        int g8 = lane >> 3;         // group 0..7 = edge slot within octet
        int sub8 = lane & 7;        // 16B slice (8 halfs) within 128B row
        float ac[8];
        #pragma unroll
        for (int k = 0; k < 8; ++k) ac[k] = 0.f;

        int rounds = (deg + 7) >> 3;
        int j = 0;
        for (; j + 2 <= rounds; j += 2) {
            int l0 = 8 * j + g8;
            int l1 = l0 + 8;
            int   sA = __shfl(s0, l0, 64);
            float cA = __shfl(cf0, l0, 64);
            int   sB = __shfl(s0, l1, 64);
            float cB = __shfl(cf0, l1, 64);
            half8 vA = ((const half8*)(wvh + (size_t)sA * DIM))[sub8];
            half8 vB = ((const half8*)(wvh + (size_t)sB * DIM))[sub8];
            #pragma unroll
            for (int k = 0; k < 8; ++k) ac[k] += (float)vA[k] * cA;
            #pragma unroll
            for (int k = 0; k < 8; ++k) ac[k] += (float)vB[k] * cB;
        }
        if (j < rounds) {
            int l0 = 8 * j + g8;
            int   sA = __shfl(s0, l0, 64);
            float cA = __shfl(cf0, l0, 64);
            half8 vA = ((const half8*)(wvh + (size_t)sA * DIM))[sub8];
            #pragma unroll
            for (int k = 0; k < 8; ++k) ac[k] += (float)vA[k] * cA;
        }
        // combine the 8 groups (disjoint edge subsets, same dims)
        #pragma unroll
        for (int off = 8; off < 64; off <<= 1) {
            #pragma unroll
            for (int k = 0; k < 8; ++k) ac[k] += __shfl_xor(ac[k], off, 64);
        }
        if (g8 == 0) {
            float4* orow = (float4*)(out + (size_t)node * DIM + sub8 * 8);
            float4 o0; o0.x = ac[0]; o0.y = ac[1]; o0.z = ac[2]; o0.w = ac[3];
            float4 o1; o1.x = ac[4]; o1.y = ac[5]; o1.z = ac[6]; o1.w = ac[7];
            orow[0] = o0; orow[1] = o1;
        }
    } else {
        double denom = 0.0;
        for (int base = 0; base < deg; base += 64) {
            int m = deg - base; if (m > 64) m = 64;
            double c = 0.0;
            if (lane < m) {
                int s = csr_src[start + base + lane];
                c = h_src[s] + hd;
            }
            #pragma unroll
            for (int off = 32; off > 0; off >>= 1) c += __shfl_xor(c, off, 64);
            denom += c;
        }
        double inv = 1.0 / denom;
        float acc = 0.f;
        for (int base = 0; base < deg; base += 64) {
            int m = deg - base; if (m > 64) m = 64;
            int s1 = 0; float cf1 = 0.f;
            if (lane < m) {
                s1 = csr_src[start + base + lane];
                cf1 = (float)((h_src[s1] + hd) * inv);
            }
            for (int j = 0; j < m; ++j) {
                int s = lane_bci(s1, j);
                float cf = lane_bcf(cf1, j);
                acc += (float)wvh[(size_t)s * DIM + lane] * cf;
            }
        }
        out[(size_t)node * DIM + lane] = acc;
    }
}

// ---------------------------------------------------------------------------
// Launch — 6 dispatches: memset, hist, node_wave(+vec), scan, build, gather.
// ---------------------------------------------------------------------------
extern "C" void kernel_launch(void* const* d_in, const int* in_sizes, int n_in,
                              void* d_out, int out_size, void* d_ws, size_t ws_size,
                              hipStream_t stream) {
    const float* d_u = (const float*)d_in[0];
    const float* p_u = (const float*)d_in[1];
    const float* w_q = (const float*)d_in[2];
    const float* w_k = (const float*)d_in[3];
    const float* w_v = (const float*)d_in[4];
    const float* e1  = (const float*)d_in[5];
    const float* e2  = (const float*)d_in[6];
    const int*   src = (const int*)d_in[7];
    const int*   dst = (const int*)d_in[8];
    float* out = (float*)d_out;

    // Workspace: doubles first (8B aligned), then halfs, then ints.
    double* h_src  = (double*)d_ws;
    double* h_dst  = h_src + N_NODES;
    _Float16* wvh  = (_Float16*)(h_dst + N_NODES);    // N_NODES*DIM halfs
    int*    cnt    = (int*)(wvh + (size_t)N_NODES * DIM);
    int*    row    = cnt + N_NODES;
    int*    cnt8   = row + N_NODES;                   // NCOPY*N_NODES ints
    unsigned int* pub = (unsigned int*)(cnt8 + (size_t)NCOPY * N_NODES); // 128
    int*    rank   = (int*)pub + 128;                 // N_EDGES ints
    int*    csr_src= rank + N_EDGES;                  // N_EDGES ints

    // zero cnt8 + pub in one memset (contiguous)
    hipMemsetAsync(cnt8, 0, sizeof(int) * ((size_t)NCOPY * N_NODES + 128),
                   stream);

    hist_kernel<<<HIST_BLKS, 256, 0, stream>>>(dst, cnt8, rank);

    node_wave<<<1024, 256, 0, stream>>>(
        d_u, p_u, w_v, w_q, w_k, e1, e2, h_src, h_dst, wvh);

    scan_kernel<<<N_SCAN_BLKS, SCAN_BLK, 0, stream>>>(cnt8, cnt, row, pub);

    build_kernel<<<(N_EDGES + 255) / 256, 256, 0, stream>>>(
        src, dst, row, cnt8, rank, csr_src);

    node_gather<<<(N_NODES * 64 + 255) / 256, 256, 0, stream>>>(
        row, cnt, csr_src, h_src, h_dst, wvh, out);
}